// Round 6
// baseline (968.188 us; speedup 1.0000x reference)
//
#include <hip/hip_runtime.h>
#include <hip/hip_bf16.h>
#include <cstdio>

typedef unsigned short u16;
typedef __attribute__((ext_vector_type(4))) float f32x4;
typedef __attribute__((ext_vector_type(8))) short s16x8;

__device__ __forceinline__ u16 bf16b(float f) {
  union { float f; unsigned u; } c; c.f = f;
  unsigned u = c.u;
  return (u16)((u + 0x7FFFu + ((u >> 16) & 1u)) >> 16);
}

__device__ __forceinline__ void load16(const void* g, void* l) {
  __builtin_amdgcn_global_load_lds(
      (const __attribute__((address_space(1))) void*)g,
      (__attribute__((address_space(3))) void*)l, 16, 0, 0);
}

// lgkmcnt-only barrier: global loads stay IN FLIGHT across it
#define BAR() asm volatile("s_waitcnt lgkmcnt(0)\n\ts_barrier" ::: "memory")

// ---------------- converters (x and W fused into one launch) ----------------

__global__ __launch_bounds__(256) void cvt_all_k(const float* __restrict__ x,
                                                 const float* __restrict__ Wq,
                                                 const float* __restrict__ Wk,
                                                 const float* __restrict__ Wv,
                                                 u16* __restrict__ xb,
                                                 u16* __restrict__ Wcat) {
  int bid = blockIdx.x;
  if (bid < 16384) {
    long i = ((long)bid * 256 + threadIdx.x) * 4;
    float4 f = *(const float4*)&x[i];
    unsigned lo = (unsigned)bf16b(f.x) | ((unsigned)bf16b(f.y) << 16);
    unsigned hi = (unsigned)bf16b(f.z) | ((unsigned)bf16b(f.w) << 16);
    uint2 v; v.x = lo; v.y = hi;
    *(uint2*)&xb[i] = v;
  } else {
    int idx = (bid - 16384) * 256 + threadIdx.x;  // 640*512
    int nn = idx >> 9, k = idx & 511;
    float v;
    if (nn < 64)       v = Wq[k * 64 + nn];
    else if (nn < 128) v = Wk[k * 64 + (nn - 64)];
    else               v = Wv[k * 512 + (nn - 128)];
    Wcat[idx] = bf16b(v);
  }
}

// ---------------- projection GEMM: C[m,n] = sum_k A[m,k]*B[n,k] ----------------
// writes Qb/Kb bf16 row-major and Vt TRANSPOSED ([b][c][n]) directly.
__global__ __launch_bounds__(256, 2) void projGemm(
    const u16* __restrict__ A, const u16* __restrict__ B,
    u16* __restrict__ Qb, u16* __restrict__ Kb, u16* __restrict__ Vt,
    const float* __restrict__ bq, const float* __restrict__ bk,
    const float* __restrict__ bv) {
  constexpr int BM = 128, BN = 128, FM = 4, FN = 4;
  __shared__ __align__(16) u16 At[BM * 64];
  __shared__ __align__(16) u16 Bt[BN * 64];
  const int tid = threadIdx.x;
  const int lane = tid & 63, w = tid >> 6;
  const int wr = w >> 1, wc = w & 1;
  const int l15 = lane & 15, lhi = lane >> 4;
  const long m0 = (long)blockIdx.x * BM;
  const long n0 = (long)blockIdx.y * BN;

  f32x4 acc[FM][FN] = {};

  for (int k0 = 0; k0 < 512; k0 += 64) {
#pragma unroll
    for (int it = 0; it < 8; ++it) {
      int q = it * 256 + tid;
      if (q < BM * 8) {
        int row = q >> 3, c8 = q & 7;
        load16(A + (m0 + row) * 512 + k0 + c8 * 8, &At[q * 8]);
      } else {
        int q2 = q - BM * 8;
        int row = q2 >> 3, c8 = q2 & 7;
        load16(B + (n0 + row) * 512 + k0 + c8 * 8, &Bt[q2 * 8]);
      }
    }
    __syncthreads();
#pragma unroll
    for (int kk = 0; kk < 64; kk += 32) {
      s16x8 af[FM], bf[FN];
#pragma unroll
      for (int i = 0; i < FM; ++i)
        af[i] = *(const s16x8*)&At[(wr * 64 + i * 16 + l15) * 64 + kk + lhi * 8];
#pragma unroll
      for (int j = 0; j < FN; ++j)
        bf[j] = *(const s16x8*)&Bt[(wc * 64 + j * 16 + l15) * 64 + kk + lhi * 8];
#pragma unroll
      for (int i = 0; i < FM; ++i)
#pragma unroll
        for (int j = 0; j < FN; ++j)
          acc[i][j] = __builtin_amdgcn_mfma_f32_16x16x32_bf16(af[i], bf[j],
                                                              acc[i][j], 0, 0, 0);
    }
    __syncthreads();
  }

#pragma unroll
  for (int i = 0; i < FM; ++i) {
#pragma unroll
    for (int j = 0; j < FN; ++j) {
      long mm = m0 + wr * 64 + i * 16 + lhi * 4;
      long nn = n0 + wc * 64 + j * 16 + l15;
      if (nn < 64) {
        float bb = bq[nn];
#pragma unroll
        for (int r = 0; r < 4; ++r)
          Qb[(mm + r) * 64 + nn] = bf16b(acc[i][j][r] + bb);
      } else if (nn < 128) {
        float bb = bk[nn - 64];
#pragma unroll
        for (int r = 0; r < 4; ++r)
          Kb[(mm + r) * 64 + nn - 64] = bf16b(acc[i][j][r] + bb);
      } else {
        long c = nn - 128;
        float bb = bv[c];
        unsigned u01 = (unsigned)bf16b(acc[i][j][0] + bb) |
                       ((unsigned)bf16b(acc[i][j][1] + bb) << 16);
        unsigned u23 = (unsigned)bf16b(acc[i][j][2] + bb) |
                       ((unsigned)bf16b(acc[i][j][3] + bb) << 16);
        uint2 u; u.x = u01; u.y = u23;
        *(uint2*)&Vt[(mm >> 12) * 512 * 4096 + c * 4096 + (mm & 4095)] = u;
      }
    }
  }
}

// ---------------- softmax row stats (over j) via S recompute ----------------
__global__ __launch_bounds__(256, 2) void stats_k(const u16* __restrict__ Qb,
                                                  const u16* __restrict__ Kb,
                                                  float* __restrict__ m_part,
                                                  float* __restrict__ l_part) {
  const int b = blockIdx.z, jc = blockIdx.y;
  const long i0 = (long)blockIdx.x * 128;
  const u16* Q = Qb + (long)b * 4096 * 64;
  const u16* Kp = Kb + (long)b * 4096 * 64;
  __shared__ __align__(16) u16 Qt[128 * 64];
  __shared__ __align__(16) u16 Kt[128 * 64];
  const int tid = threadIdx.x, lane = tid & 63, w = tid >> 6;
  const int l15 = lane & 15, lhi = lane >> 4;

#pragma unroll
  for (int it = 0; it < 4; ++it) {
    int q = it * 256 + tid;
    int row = q >> 3, c8 = q & 7;
    load16(Q + (i0 + row) * 64 + c8 * 8, &Qt[q * 8]);
  }

  float mrun[2][4], lrun[2][4];
#pragma unroll
  for (int i = 0; i < 2; ++i)
#pragma unroll
    for (int r = 0; r < 4; ++r) { mrun[i][r] = -1e30f; lrun[i][r] = 0.f; }

  for (int jt = 0; jt < 8; ++jt) {
    long j0 = (long)jc * 1024 + jt * 128;
#pragma unroll
    for (int it = 0; it < 4; ++it) {
      int q = it * 256 + tid;
      int row = q >> 3, c8 = q & 7;
      load16(Kp + (j0 + row) * 64 + c8 * 8, &Kt[q * 8]);
    }
    __syncthreads();
    f32x4 acc[2][8] = {};
#pragma unroll
    for (int kk = 0; kk < 64; kk += 32) {
      s16x8 af[2], bf[8];
#pragma unroll
      for (int i = 0; i < 2; ++i)
        af[i] = *(const s16x8*)&Qt[(w * 32 + i * 16 + l15) * 64 + kk + lhi * 8];
#pragma unroll
      for (int j = 0; j < 8; ++j)
        bf[j] = *(const s16x8*)&Kt[(j * 16 + l15) * 64 + kk + lhi * 8];
#pragma unroll
      for (int i = 0; i < 2; ++i)
#pragma unroll
        for (int j = 0; j < 8; ++j)
          acc[i][j] = __builtin_amdgcn_mfma_f32_16x16x32_bf16(af[i], bf[j],
                                                              acc[i][j], 0, 0, 0);
    }
#pragma unroll
    for (int i = 0; i < 2; ++i)
#pragma unroll
      for (int r = 0; r < 4; ++r) {
        float tm = acc[i][0][r];
#pragma unroll
        for (int j = 1; j < 8; ++j) tm = fmaxf(tm, acc[i][j][r]);
        float mo = mrun[i][r];
        float mn = fmaxf(mo, tm);
        float s = 0.f;
#pragma unroll
        for (int j = 0; j < 8; ++j) s += __expf(acc[i][j][r] - mn);
        lrun[i][r] = lrun[i][r] * __expf(mo - mn) + s;
        mrun[i][r] = mn;
      }
    __syncthreads();
  }

#pragma unroll
  for (int i = 0; i < 2; ++i)
#pragma unroll
    for (int r = 0; r < 4; ++r) {
      float m = mrun[i][r], l = lrun[i][r];
#pragma unroll
      for (int d = 1; d < 16; d <<= 1) {
        float mo = __shfl_xor(m, d);
        float lo = __shfl_xor(l, d);
        float mn = fmaxf(m, mo);
        l = l * __expf(m - mn) + lo * __expf(mo - mn);
        m = mn;
      }
      if (l15 == 0) {
        long ig = i0 + w * 32 + i * 16 + lhi * 4 + r;
        long idx = ((long)(b * 4 + jc)) * 4096 + ig;
        m_part[idx] = m;
        l_part[idx] = l;
      }
    }
}

__global__ __launch_bounds__(256) void merge_k(const float* __restrict__ m_part,
                                               const float* __restrict__ l_part,
                                               float* __restrict__ mfin,
                                               float* __restrict__ linv) {
  int idx = blockIdx.x * 256 + threadIdx.x;  // 8*4096
  int b = idx >> 12, i = idx & 4095;
  float m = -1e30f, l = 0.f;
#pragma unroll
  for (int jc = 0; jc < 4; ++jc) {
    long o = ((long)(b * 4 + jc)) * 4096 + i;
    float mp = m_part[o], lp = l_part[o];
    float mn = fmaxf(m, mp);
    l = l * __expf(m - mn) + lp * __expf(mp - mn);
    m = mn;
  }
  mfin[idx] = m;
  linv[idx] = 1.0f / l;
}

// ---------------- fused P·V — occupancy-first restructure ----------------
// 4-wave (256 thr) block, tile j=64 x c=256, LDS 40KB -> 3 blocks/CU.
// K,Q fragments global->register (GEMM1 fully LDS-free). V single-buffered
// in LDS with T14 reg-staging (load early / ds_write after post-GEMM2 bar).
// 2 lgkm-only barriers per iter; no vmcnt(0) in loop.
//
// PV_STEP(T, QFC, QFN): prefetch V(t+1)->vreg, Q(t+1)->QFN; GEMM1 from regs;
// exp-epilogue -> Pl (swizzled); BAR; GEMM2 (setprio); BAR; ds_write V(t+1).
#define PV_STEP(T, QFC, QFN)                                                   \
  {                                                                            \
    const int i_base = (T) * 64;                                               \
    const int tnx = ((T) + 1) & 63;                                            \
    _Pragma("unroll")                                                          \
    for (int p = 0; p < 8; ++p) {                                              \
      int q = p * 256 + tid; int r = q >> 3, col = q & 7;                      \
      vreg[p] = *(const uint4*)&Vg[(long)r * 4096 + tnx * 64 + col * 8];       \
    }                                                                          \
    _Pragma("unroll")                                                          \
    for (int fi = 0; fi < 2; ++fi)                                             \
      _Pragma("unroll")                                                        \
      for (int kx = 0; kx < 2; ++kx)                                           \
        QFN[fi][kx] = *(const s16x8*)&Qg[(long)(tnx * 64 + wi * 32 + fi * 16 + \
                                                l15) * 64 + kx * 32 + lhi * 8];\
    f32x4 acc1[2][2] = {};                                                     \
    _Pragma("unroll")                                                          \
    for (int kx = 0; kx < 2; ++kx)                                             \
      _Pragma("unroll")                                                        \
      for (int fi = 0; fi < 2; ++fi)                                           \
        _Pragma("unroll")                                                      \
        for (int fj = 0; fj < 2; ++fj)                                         \
          acc1[fi][fj] = __builtin_amdgcn_mfma_f32_16x16x32_bf16(              \
              QFC[fi][kx], kf[fj][kx], acc1[fi][fj], 0, 0, 0);                 \
    _Pragma("unroll")                                                          \
    for (int fi = 0; fi < 2; ++fi) {                                           \
      int i0l = wi * 32 + fi * 16 + lhi * 4;                                   \
      f32x4 mv = *(const f32x4*)&mg[i_base + i0l];                             \
      f32x4 lv = *(const f32x4*)&lg[i_base + i0l];                             \
      _Pragma("unroll")                                                        \
      for (int fj = 0; fj < 2; ++fj) {                                         \
        int j = wjj * 32 + fj * 16 + l15;                                      \
        float p0 = __expf(acc1[fi][fj][0] - mv[0]) * lv[0];                    \
        float p1 = __expf(acc1[fi][fj][1] - mv[1]) * lv[1];                    \
        float p2 = __expf(acc1[fi][fj][2] - mv[2]) * lv[2];                    \
        float p3 = __expf(acc1[fi][fj][3] - mv[3]) * lv[3];                    \
        uint2 u;                                                               \
        u.x = (unsigned)bf16b(p0) | ((unsigned)bf16b(p1) << 16);               \
        u.y = (unsigned)bf16b(p2) | ((unsigned)bf16b(p3) << 16);               \
        *(uint2*)((char*)Pl + j * 128 + ((i0l * 2) ^ ((j & 7) << 4))) = u;     \
      }                                                                        \
    }                                                                          \
    BAR();                                                                     \
    __builtin_amdgcn_s_setprio(1);                                             \
    _Pragma("unroll")                                                          \
    for (int kx = 0; kx < 2; ++kx) {                                           \
      s16x8 pa[4];                                                             \
      _Pragma("unroll")                                                        \
      for (int fm = 0; fm < 4; ++fm) {                                         \
        int pr = fm * 16 + l15;                                                \
        pa[fm] = *(const s16x8*)((const char*)Pl + pr * 128 +                  \
                                 (((kx * 32 + lhi * 8) * 2) ^                  \
                                  ((pr & 7) << 4)));                           \
      }                                                                        \
      _Pragma("unroll")                                                        \
      for (int fn = 0; fn < 4; ++fn) {                                         \
        int vr = w * 64 + fn * 16 + l15;                                       \
        s16x8 vb = *(const s16x8*)((const char*)Vc + vr * 128 +                \
                                   (((kx * 32 + lhi * 8) * 2) ^                \
                                    ((vr & 7) << 4)));                         \
        _Pragma("unroll")                                                      \
        for (int fm = 0; fm < 4; ++fm)                                         \
          acc2[fm][fn] = __builtin_amdgcn_mfma_f32_16x16x32_bf16(              \
              pa[fm], vb, acc2[fm][fn], 0, 0, 0);                              \
      }                                                                        \
    }                                                                          \
    __builtin_amdgcn_s_setprio(0);                                             \
    BAR();                                                                     \
    _Pragma("unroll")                                                          \
    for (int p = 0; p < 8; ++p) {                                              \
      int q = p * 256 + tid; int r = q >> 3, col = q & 7;                      \
      *(uint4*)((char*)Vc + r * 128 + ((col * 16) ^ ((r & 7) << 4))) = vreg[p];\
    }                                                                          \
  }

__global__ __launch_bounds__(256, 3) void fusedPV(
    const u16* __restrict__ Qb, const u16* __restrict__ Kb,
    const u16* __restrict__ Vt, const float* __restrict__ mfin,
    const float* __restrict__ lnv, const float* __restrict__ x,
    const float* __restrict__ gamma, float* __restrict__ out) {
  __shared__ __align__(16) u16 Vc[256 * 64];  // 32 KB, swizzled 128B rows
  __shared__ __align__(16) u16 Pl[64 * 64];   // 8 KB, swizzled 128B rows
  const int tid = threadIdx.x, lane = tid & 63, w = tid >> 6;
  const int l15 = lane & 15, lhi = lane >> 4;
  const int wi = w & 1, wjj = w >> 1;  // GEMM1 wave roles
  // XCD remap: 1024 blocks = 8 XCDs x 128; XCD x owns batch x's V (4MB = L2)
  const int s = blockIdx.x + 64 * blockIdx.y + 128 * blockIdx.z;
  const int pi = (s & 7) * 128 + (s >> 3);
  const int b = pi >> 7;
  const long c0 = (long)((pi >> 6) & 1) * 256;
  const long j0 = (long)(pi & 63) * 64;
  const u16* Qg = Qb + (long)b * 4096 * 64;
  const u16* Kg = Kb + (long)b * 4096 * 64;
  const u16* Vg = Vt + (long)b * 512 * 4096 + c0 * 4096;
  const float* mg = mfin + (long)b * 4096;
  const float* lg = lnv + (long)b * 4096;
  const float gma = gamma[0];

  // loop-invariant K fragments (global -> reg, per-lane 16B contiguous)
  s16x8 kf[2][2];
#pragma unroll
  for (int fj = 0; fj < 2; ++fj)
#pragma unroll
    for (int kx = 0; kx < 2; ++kx)
      kf[fj][kx] = *(const s16x8*)&Kg[(j0 + wjj * 32 + fj * 16 + l15) * 64 +
                                      kx * 32 + lhi * 8];

  uint4 vreg[8];
  s16x8 qfA[2][2], qfB[2][2];
  // prologue: V(0) -> regs -> LDS; Q(0) -> qfA
#pragma unroll
  for (int p = 0; p < 8; ++p) {
    int q = p * 256 + tid; int r = q >> 3, col = q & 7;
    vreg[p] = *(const uint4*)&Vg[(long)r * 4096 + col * 8];
  }
#pragma unroll
  for (int fi = 0; fi < 2; ++fi)
#pragma unroll
    for (int kx = 0; kx < 2; ++kx)
      qfA[fi][kx] = *(const s16x8*)&Qg[(long)(wi * 32 + fi * 16 + l15) * 64 +
                                       kx * 32 + lhi * 8];
#pragma unroll
  for (int p = 0; p < 8; ++p) {
    int q = p * 256 + tid; int r = q >> 3, col = q & 7;
    *(uint4*)((char*)Vc + r * 128 + ((col * 16) ^ ((r & 7) << 4))) = vreg[p];
  }

  f32x4 acc2[4][4] = {};

  for (int t = 0; t < 64; t += 2) {
    PV_STEP(t, qfA, qfB);
    PV_STEP(t + 1, qfB, qfA);
  }

  // final epilogue: out = gamma*acc2 + x
#pragma unroll
  for (int fm = 0; fm < 4; ++fm) {
#pragma unroll
    for (int fn = 0; fn < 4; ++fn) {
      long j = j0 + fm * 16 + lhi * 4;
      long c = c0 + w * 64 + fn * 16 + l15;
#pragma unroll
      for (int r = 0; r < 4; ++r) {
        long o = ((long)b * 4096 + j + r) * 512 + c;
        out[o] = gma * acc2[fm][fn][r] + x[o];
      }
    }
  }
}

// ---------------- host ----------------

extern "C" void kernel_launch(void* const* d_in, const int* in_sizes, int n_in,
                              void* d_out, int out_size, void* d_ws,
                              size_t ws_size, hipStream_t stream) {
  const float* x = (const float*)d_in[0];
  const float* Wq = (const float*)d_in[1];
  const float* bq = (const float*)d_in[2];
  const float* Wk = (const float*)d_in[3];
  const float* bk = (const float*)d_in[4];
  const float* Wv = (const float*)d_in[5];
  const float* bv = (const float*)d_in[6];
  const float* gamma = (const float*)d_in[7];
  float* out = (float*)d_out;

  char* ws = (char*)d_ws;
  size_t off = 0;
  auto alloc = [&](size_t bytes) {
    char* p = ws + off;
    off += (bytes + 255) & ~(size_t)255;
    return p;
  };
  u16* xb = (u16*)alloc((size_t)32768 * 512 * 2);        // 32 MB
  u16* Wcat = (u16*)alloc((size_t)640 * 512 * 2);        // 640 KB
  u16* Qb = (u16*)alloc((size_t)8 * 4096 * 64 * 2);      // 4 MB
  u16* Kb = (u16*)alloc((size_t)8 * 4096 * 64 * 2);      // 4 MB
  u16* Vt = (u16*)alloc((size_t)8 * 512 * 4096 * 2);     // 32 MB
  float* m_part = (float*)alloc((size_t)8 * 4 * 4096 * 4);
  float* l_part = (float*)alloc((size_t)8 * 4 * 4096 * 4);
  float* mfin = (float*)alloc((size_t)8 * 4096 * 4);
  float* lnv = (float*)alloc((size_t)8 * 4096 * 4);
  if (off > ws_size) {
    fprintf(stderr, "kernel_launch: ws too small: need %zu have %zu\n", off,
            ws_size);
    return;
  }

  // 1) dtype conversions (x + W in one launch)
  cvt_all_k<<<16384 + 1280, 256, 0, stream>>>(x, Wq, Wk, Wv, xb, Wcat);
  // 2) fused q/k/v projection GEMM (M=32768, N=640, K=512); writes Vt directly
  projGemm<<<dim3(256, 5, 1), 256, 0, stream>>>(xb, Wcat, Qb, Kb, Vt, bq, bk,
                                                bv);
  // 3) softmax row stats (recompute S)
  stats_k<<<dim3(32, 4, 8), 256, 0, stream>>>(Qb, Kb, m_part, l_part);
  merge_k<<<128, 256, 0, stream>>>(m_part, l_part, mfin, lnv);
  // 4) fused P recompute + P·V + residual epilogue (all 8 batches)
  fusedPV<<<dim3(64, 2, 8), 256, 0, stream>>>(Qb, Kb, Vt, mfin, lnv, x,
                                              gamma, out);
}

// Round 7
// 304.578 us; speedup vs baseline: 3.1788x; 3.1788x over previous
//
#include <hip/hip_runtime.h>
#include <hip/hip_bf16.h>
#include <cstdio>

typedef unsigned short u16;
typedef __attribute__((ext_vector_type(4))) float f32x4;
typedef __attribute__((ext_vector_type(8))) short s16x8;

__device__ __forceinline__ u16 bf16b(float f) {
  union { float f; unsigned u; } c; c.f = f;
  unsigned u = c.u;
  return (u16)((u + 0x7FFFu + ((u >> 16) & 1u)) >> 16);
}

__device__ __forceinline__ void load16(const void* g, void* l) {
  __builtin_amdgcn_global_load_lds(
      (const __attribute__((address_space(1))) void*)g,
      (__attribute__((address_space(3))) void*)l, 16, 0, 0);
}

// ---------------- converters (x and W fused into one launch) ----------------

__global__ __launch_bounds__(256) void cvt_all_k(const float* __restrict__ x,
                                                 const float* __restrict__ Wq,
                                                 const float* __restrict__ Wk,
                                                 const float* __restrict__ Wv,
                                                 u16* __restrict__ xb,
                                                 u16* __restrict__ Wcat) {
  int bid = blockIdx.x;
  if (bid < 16384) {
    long i = ((long)bid * 256 + threadIdx.x) * 4;
    float4 f = *(const float4*)&x[i];
    unsigned lo = (unsigned)bf16b(f.x) | ((unsigned)bf16b(f.y) << 16);
    unsigned hi = (unsigned)bf16b(f.z) | ((unsigned)bf16b(f.w) << 16);
    uint2 v; v.x = lo; v.y = hi;
    *(uint2*)&xb[i] = v;
  } else {
    int idx = (bid - 16384) * 256 + threadIdx.x;  // 640*512
    int nn = idx >> 9, k = idx & 511;
    float v;
    if (nn < 64)       v = Wq[k * 64 + nn];
    else if (nn < 128) v = Wk[k * 64 + (nn - 64)];
    else               v = Wv[k * 512 + (nn - 128)];
    Wcat[idx] = bf16b(v);
  }
}

// ---------------- projection GEMM: C[m,n] = sum_k A[m,k]*B[n,k] ----------------
// writes Qb/Kb bf16 row-major and Vt TRANSPOSED ([b][c][n]) directly.
__global__ __launch_bounds__(256, 2) void projGemm(
    const u16* __restrict__ A, const u16* __restrict__ B,
    u16* __restrict__ Qb, u16* __restrict__ Kb, u16* __restrict__ Vt,
    const float* __restrict__ bq, const float* __restrict__ bk,
    const float* __restrict__ bv) {
  constexpr int BM = 128, BN = 128, FM = 4, FN = 4;
  __shared__ __align__(16) u16 At[BM * 64];
  __shared__ __align__(16) u16 Bt[BN * 64];
  const int tid = threadIdx.x;
  const int lane = tid & 63, w = tid >> 6;
  const int wr = w >> 1, wc = w & 1;
  const int l15 = lane & 15, lhi = lane >> 4;
  const long m0 = (long)blockIdx.x * BM;
  const long n0 = (long)blockIdx.y * BN;

  f32x4 acc[FM][FN] = {};

  for (int k0 = 0; k0 < 512; k0 += 64) {
#pragma unroll
    for (int it = 0; it < 8; ++it) {
      int q = it * 256 + tid;
      if (q < BM * 8) {
        int row = q >> 3, c8 = q & 7;
        load16(A + (m0 + row) * 512 + k0 + c8 * 8, &At[q * 8]);
      } else {
        int q2 = q - BM * 8;
        int row = q2 >> 3, c8 = q2 & 7;
        load16(B + (n0 + row) * 512 + k0 + c8 * 8, &Bt[q2 * 8]);
      }
    }
    __syncthreads();
#pragma unroll
    for (int kk = 0; kk < 64; kk += 32) {
      s16x8 af[FM], bf[FN];
#pragma unroll
      for (int i = 0; i < FM; ++i)
        af[i] = *(const s16x8*)&At[(wr * 64 + i * 16 + l15) * 64 + kk + lhi * 8];
#pragma unroll
      for (int j = 0; j < FN; ++j)
        bf[j] = *(const s16x8*)&Bt[(wc * 64 + j * 16 + l15) * 64 + kk + lhi * 8];
#pragma unroll
      for (int i = 0; i < FM; ++i)
#pragma unroll
        for (int j = 0; j < FN; ++j)
          acc[i][j] = __builtin_amdgcn_mfma_f32_16x16x32_bf16(af[i], bf[j],
                                                              acc[i][j], 0, 0, 0);
    }
    __syncthreads();
  }

#pragma unroll
  for (int i = 0; i < FM; ++i) {
#pragma unroll
    for (int j = 0; j < FN; ++j) {
      long mm = m0 + wr * 64 + i * 16 + lhi * 4;
      long nn = n0 + wc * 64 + j * 16 + l15;
      if (nn < 64) {
        float bb = bq[nn];
#pragma unroll
        for (int r = 0; r < 4; ++r)
          Qb[(mm + r) * 64 + nn] = bf16b(acc[i][j][r] + bb);
      } else if (nn < 128) {
        float bb = bk[nn - 64];
#pragma unroll
        for (int r = 0; r < 4; ++r)
          Kb[(mm + r) * 64 + nn - 64] = bf16b(acc[i][j][r] + bb);
      } else {
        long c = nn - 128;
        float bb = bv[c];
        unsigned u01 = (unsigned)bf16b(acc[i][j][0] + bb) |
                       ((unsigned)bf16b(acc[i][j][1] + bb) << 16);
        unsigned u23 = (unsigned)bf16b(acc[i][j][2] + bb) |
                       ((unsigned)bf16b(acc[i][j][3] + bb) << 16);
        uint2 u; u.x = u01; u.y = u23;
        *(uint2*)&Vt[(mm >> 12) * 512 * 4096 + c * 4096 + (mm & 4095)] = u;
      }
    }
  }
}

// ---------------- softmax row stats (over j) via S recompute ----------------
__global__ __launch_bounds__(256, 2) void stats_k(const u16* __restrict__ Qb,
                                                  const u16* __restrict__ Kb,
                                                  float* __restrict__ m_part,
                                                  float* __restrict__ l_part) {
  const int b = blockIdx.z, jc = blockIdx.y;
  const long i0 = (long)blockIdx.x * 128;
  const u16* Q = Qb + (long)b * 4096 * 64;
  const u16* Kp = Kb + (long)b * 4096 * 64;
  __shared__ __align__(16) u16 Qt[128 * 64];
  __shared__ __align__(16) u16 Kt[128 * 64];
  const int tid = threadIdx.x, lane = tid & 63, w = tid >> 6;
  const int l15 = lane & 15, lhi = lane >> 4;

#pragma unroll
  for (int it = 0; it < 4; ++it) {
    int q = it * 256 + tid;
    int row = q >> 3, c8 = q & 7;
    load16(Q + (i0 + row) * 64 + c8 * 8, &Qt[q * 8]);
  }

  float mrun[2][4], lrun[2][4];
#pragma unroll
  for (int i = 0; i < 2; ++i)
#pragma unroll
    for (int r = 0; r < 4; ++r) { mrun[i][r] = -1e30f; lrun[i][r] = 0.f; }

  for (int jt = 0; jt < 8; ++jt) {
    long j0 = (long)jc * 1024 + jt * 128;
#pragma unroll
    for (int it = 0; it < 4; ++it) {
      int q = it * 256 + tid;
      int row = q >> 3, c8 = q & 7;
      load16(Kp + (j0 + row) * 64 + c8 * 8, &Kt[q * 8]);
    }
    __syncthreads();
    f32x4 acc[2][8] = {};
#pragma unroll
    for (int kk = 0; kk < 64; kk += 32) {
      s16x8 af[2], bf[8];
#pragma unroll
      for (int i = 0; i < 2; ++i)
        af[i] = *(const s16x8*)&Qt[(w * 32 + i * 16 + l15) * 64 + kk + lhi * 8];
#pragma unroll
      for (int j = 0; j < 8; ++j)
        bf[j] = *(const s16x8*)&Kt[(j * 16 + l15) * 64 + kk + lhi * 8];
#pragma unroll
      for (int i = 0; i < 2; ++i)
#pragma unroll
        for (int j = 0; j < 8; ++j)
          acc[i][j] = __builtin_amdgcn_mfma_f32_16x16x32_bf16(af[i], bf[j],
                                                              acc[i][j], 0, 0, 0);
    }
#pragma unroll
    for (int i = 0; i < 2; ++i)
#pragma unroll
      for (int r = 0; r < 4; ++r) {
        float tm = acc[i][0][r];
#pragma unroll
        for (int j = 1; j < 8; ++j) tm = fmaxf(tm, acc[i][j][r]);
        float mo = mrun[i][r];
        float mn = fmaxf(mo, tm);
        float s = 0.f;
#pragma unroll
        for (int j = 0; j < 8; ++j) s += __expf(acc[i][j][r] - mn);
        lrun[i][r] = lrun[i][r] * __expf(mo - mn) + s;
        mrun[i][r] = mn;
      }
    __syncthreads();
  }

#pragma unroll
  for (int i = 0; i < 2; ++i)
#pragma unroll
    for (int r = 0; r < 4; ++r) {
      float m = mrun[i][r], l = lrun[i][r];
#pragma unroll
      for (int d = 1; d < 16; d <<= 1) {
        float mo = __shfl_xor(m, d);
        float lo = __shfl_xor(l, d);
        float mn = fmaxf(m, mo);
        l = l * __expf(m - mn) + lo * __expf(mo - mn);
        m = mn;
      }
      if (l15 == 0) {
        long ig = i0 + w * 32 + i * 16 + lhi * 4 + r;
        long idx = ((long)(b * 4 + jc)) * 4096 + ig;
        m_part[idx] = m;
        l_part[idx] = l;
      }
    }
}

__global__ __launch_bounds__(256) void merge_k(const float* __restrict__ m_part,
                                               const float* __restrict__ l_part,
                                               float* __restrict__ mfin,
                                               float* __restrict__ linv) {
  int idx = blockIdx.x * 256 + threadIdx.x;  // 8*4096
  int b = idx >> 12, i = idx & 4095;
  float m = -1e30f, l = 0.f;
#pragma unroll
  for (int jc = 0; jc < 4; ++jc) {
    long o = ((long)(b * 4 + jc)) * 4096 + i;
    float mp = m_part[o], lp = l_part[o];
    float mn = fmaxf(m, mp);
    l = l * __expf(m - mn) + lp * __expf(mp - mn);
    m = mn;
  }
  mfin[idx] = m;
  linv[idx] = 1.0f / l;
}

// ---------------- fused P·V (r3 structure + kf-regs + XCD swizzle) ----------
// Block: out[b, j0:j0+128, c0:c0+256]; 4 waves; LDS 56KB -> 2 blocks/CU
// (stagger between the two co-resident blocks hides barriers).
// Loop i in 64-chunks: stage Q,V -> sync -> GEMM1 (K in regs) -> exp-epilogue
// -> Pl -> sync -> GEMM2 (setprio) -> sync.
__global__ __launch_bounds__(256, 2) void fusedPV(
    const u16* __restrict__ Qb, const u16* __restrict__ Kb,
    const u16* __restrict__ Vt, const float* __restrict__ mfin,
    const float* __restrict__ lnv, const float* __restrict__ x,
    const float* __restrict__ gamma, float* __restrict__ out) {
  __shared__ __align__(16) u16 Qc[64 * 64];    // 8 KB
  __shared__ __align__(16) u16 Vc[256 * 64];   // 32 KB
  __shared__ __align__(16) u16 Pl[128 * 64];   // 16 KB (K staging alias)
  const int tid = threadIdx.x, lane = tid & 63, w = tid >> 6;
  const int l15 = lane & 15, lhi = lane >> 4;
  const int wi = w & 1, wj = w >> 1, wc = w & 1;  // wj in 0..1
  // XCD remap: 512 blocks = 8 XCDs x 64; XCD x owns batch x (V 4MB = its L2)
  const int s = blockIdx.x + 32 * (blockIdx.y + 2 * blockIdx.z);
  const int pi = (s & 7) * 64 + (s >> 3);
  const int b = pi >> 6;
  const long c0 = (long)((pi >> 5) & 1) * 256;
  const long j0 = (long)(pi & 31) * 128;
  const u16* Qg = Qb + (long)b * 4096 * 64;
  const u16* Kg = Kb + (long)b * 4096 * 64;
  const u16* Vg = Vt + (long)b * 512 * 4096;
  const float* mg = mfin + (long)b * 4096;
  const float* lg = lnv + (long)b * 4096;
  const float gma = gamma[0];

  // ---- prologue: stage K tile (128 x 128B) through Pl, hoist to regs ----
#pragma unroll
  for (int p = 0; p < 4; ++p) {
    int q = p * 256 + tid;
    int r = q >> 3, col = q & 7, cg = col ^ (r & 7);
    load16(Kg + (j0 + r) * 64 + cg * 8, (char*)Pl + r * 128 + col * 16);
  }
  asm volatile("s_waitcnt vmcnt(0) lgkmcnt(0)\n\ts_barrier" ::: "memory");
  s16x8 kf[4][2];  // loop-invariant K fragments (32 VGPR)
#pragma unroll
  for (int fj = 0; fj < 4; ++fj)
#pragma unroll
    for (int kx = 0; kx < 2; ++kx) {
      int r = wj * 64 + fj * 16 + l15;
      kf[fj][kx] = *(const s16x8*)((const char*)Pl + r * 128 +
                                   (((kx * 32 + lhi * 8) * 2) ^ ((r & 7) << 4)));
    }
  __syncthreads();  // all kf reads done before Pl reused for P

  f32x4 acc2[4][8] = {};

  for (int t = 0; t < 64; ++t) {
    const int i_base = t * 64;
    // stage Q chunk (64 x 128B = 8KB)
#pragma unroll
    for (int p = 0; p < 2; ++p) {
      int q = p * 256 + tid;
      int r = q >> 3, col = q & 7, cg = col ^ (r & 7);
      load16(Qg + (long)(i_base + r) * 64 + cg * 8,
             (char*)Qc + r * 128 + col * 16);
    }
    // stage V chunk (256 c-rows x 128B = 32KB)
#pragma unroll
    for (int p = 0; p < 8; ++p) {
      int q = p * 256 + tid;
      int r = q >> 3, col = q & 7, cg = col ^ (r & 7);
      load16(Vg + (c0 + r) * 4096 + i_base + cg * 8,
             (char*)Vc + r * 128 + col * 16);
    }
    __syncthreads();

    // GEMM1: S[i(64)][j(128)]; wave (wi,wj): 32i x 64j; K from registers
    f32x4 acc1[2][4] = {};
#pragma unroll
    for (int kx = 0; kx < 2; ++kx) {
      s16x8 af[2];
#pragma unroll
      for (int fi = 0; fi < 2; ++fi) {
        int r = wi * 32 + fi * 16 + l15;
        af[fi] = *(const s16x8*)((const char*)Qc + r * 128 +
                                 (((kx * 32 + lhi * 8) * 2) ^ ((r & 7) << 4)));
      }
#pragma unroll
      for (int fi = 0; fi < 2; ++fi)
#pragma unroll
        for (int fj = 0; fj < 4; ++fj)
          acc1[fi][fj] = __builtin_amdgcn_mfma_f32_16x16x32_bf16(
              af[fi], kf[fj][kx], acc1[fi][fj], 0, 0, 0);
    }

    // epilogue: p = exp(s - m_i)*linv_i -> bf16 -> Pl[j][i] (swizzled)
#pragma unroll
    for (int fi = 0; fi < 2; ++fi) {
      int i0l = wi * 32 + fi * 16 + lhi * 4;
      f32x4 mv = *(const f32x4*)&mg[i_base + i0l];
      f32x4 lv = *(const f32x4*)&lg[i_base + i0l];
#pragma unroll
      for (int fj = 0; fj < 4; ++fj) {
        int j = wj * 64 + fj * 16 + l15;
        float p0 = __expf(acc1[fi][fj][0] - mv[0]) * lv[0];
        float p1 = __expf(acc1[fi][fj][1] - mv[1]) * lv[1];
        float p2 = __expf(acc1[fi][fj][2] - mv[2]) * lv[2];
        float p3 = __expf(acc1[fi][fj][3] - mv[3]) * lv[3];
        uint2 u;
        u.x = (unsigned)bf16b(p0) | ((unsigned)bf16b(p1) << 16);
        u.y = (unsigned)bf16b(p2) | ((unsigned)bf16b(p3) << 16);
        *(uint2*)((char*)Pl + j * 128 + ((i0l * 2) ^ ((j & 7) << 4))) = u;
      }
    }
    __syncthreads();

    // GEMM2: acc2 += Pl(as A; m=j) x Vc(as B; n=c)
    __builtin_amdgcn_s_setprio(1);
#pragma unroll
    for (int kx = 0; kx < 2; ++kx) {
      int kk = kx * 32;
      s16x8 pa[4];
#pragma unroll
      for (int fm = 0; fm < 4; ++fm) {
        int r = wj * 64 + fm * 16 + l15;
        pa[fm] = *(const s16x8*)((const char*)Pl + r * 128 +
                                 (((kk + lhi * 8) * 2) ^ ((r & 7) << 4)));
      }
#pragma unroll
      for (int fn = 0; fn < 8; ++fn) {
        int r = wc * 128 + fn * 16 + l15;
        s16x8 vb = *(const s16x8*)((const char*)Vc + r * 128 +
                                   (((kk + lhi * 8) * 2) ^ ((r & 7) << 4)));
#pragma unroll
        for (int fm = 0; fm < 4; ++fm)
          acc2[fm][fn] = __builtin_amdgcn_mfma_f32_16x16x32_bf16(
              pa[fm], vb, acc2[fm][fn], 0, 0, 0);
      }
    }
    __builtin_amdgcn_s_setprio(0);
    __syncthreads();
  }

  // final epilogue: out = gamma*acc2 + x
#pragma unroll
  for (int fm = 0; fm < 4; ++fm) {
#pragma unroll
    for (int fn = 0; fn < 8; ++fn) {
      long j = j0 + wj * 64 + fm * 16 + lhi * 4;
      long c = c0 + wc * 128 + fn * 16 + l15;
#pragma unroll
      for (int r = 0; r < 4; ++r) {
        long o = ((long)b * 4096 + j + r) * 512 + c;
        out[o] = gma * acc2[fm][fn][r] + x[o];
      }
    }
  }
}

// ---------------- host ----------------

extern "C" void kernel_launch(void* const* d_in, const int* in_sizes, int n_in,
                              void* d_out, int out_size, void* d_ws,
                              size_t ws_size, hipStream_t stream) {
  const float* x = (const float*)d_in[0];
  const float* Wq = (const float*)d_in[1];
  const float* bq = (const float*)d_in[2];
  const float* Wk = (const float*)d_in[3];
  const float* bk = (const float*)d_in[4];
  const float* Wv = (const float*)d_in[5];
  const float* bv = (const float*)d_in[6];
  const float* gamma = (const float*)d_in[7];
  float* out = (float*)d_out;

  char* ws = (char*)d_ws;
  size_t off = 0;
  auto alloc = [&](size_t bytes) {
    char* p = ws + off;
    off += (bytes + 255) & ~(size_t)255;
    return p;
  };
  u16* xb = (u16*)alloc((size_t)32768 * 512 * 2);        // 32 MB
  u16* Wcat = (u16*)alloc((size_t)640 * 512 * 2);        // 640 KB
  u16* Qb = (u16*)alloc((size_t)8 * 4096 * 64 * 2);      // 4 MB
  u16* Kb = (u16*)alloc((size_t)8 * 4096 * 64 * 2);      // 4 MB
  u16* Vt = (u16*)alloc((size_t)8 * 512 * 4096 * 2);     // 32 MB
  float* m_part = (float*)alloc((size_t)8 * 4 * 4096 * 4);
  float* l_part = (float*)alloc((size_t)8 * 4 * 4096 * 4);
  float* mfin = (float*)alloc((size_t)8 * 4096 * 4);
  float* lnv = (float*)alloc((size_t)8 * 4096 * 4);
  if (off > ws_size) {
    fprintf(stderr, "kernel_launch: ws too small: need %zu have %zu\n", off,
            ws_size);
    return;
  }

  // 1) dtype conversions (x + W in one launch)
  cvt_all_k<<<16384 + 1280, 256, 0, stream>>>(x, Wq, Wk, Wv, xb, Wcat);
  // 2) fused q/k/v projection GEMM (M=32768, N=640, K=512); writes Vt directly
  projGemm<<<dim3(256, 5, 1), 256, 0, stream>>>(xb, Wcat, Qb, Kb, Vt, bq, bk,
                                                bv);
  // 3) softmax row stats (recompute S)
  stats_k<<<dim3(32, 4, 8), 256, 0, stream>>>(Qb, Kb, m_part, l_part);
  merge_k<<<128, 256, 0, stream>>>(m_part, l_part, mfin, lnv);
  // 4) fused P recompute + P·V + residual epilogue (all 8 batches)
  fusedPV<<<dim3(32, 2, 8), 256, 0, stream>>>(Qb, Kb, Vt, mfin, lnv, x,
                                              gamma, out);
}